// Round 8
// baseline (56.377 us; speedup 1.0000x reference)
//
#include <hip/hip_runtime.h>
#include <math.h>

#define TT 512
#define DD 64
#define EPSF 1e-5f

typedef float f4 __attribute__((ext_vector_type(4)));

// output offsets (floats), concatenated in return order
#define O_EST  0                       // est_latent (1,2,512,64)
#define O_QIJ  (2*TT*DD)               // Q_ij (1,512,512,64)
#define O_ZHAT (O_QIJ + TT*TT*DD)      // Zhat (1,2,512,512,64)
#define O_LH   (O_ZHAT + 2*TT*TT*DD)   // lambda_h (2,64)
#define O_ME   (O_LH + 2*DD)           // mat_exp (1,2,64)

// ws layout (floats)
#define W_QBUF 0
#define W_KBUF (W_QBUF + 2*TT*DD)
#define W_CA   (W_KBUF + 2*TT*DD)          // a[d]
#define W_CB   (W_CA + DD)                 // bc[d]
#define W_CC   (W_CB + DD)                 // c1[d]
#define W_CG   (W_CC + DD)                 // lGa[d]

// ---------------- Q/K projection ----------------------------------------
__global__ __launch_bounds__(128) void afa_proj_kernel(
    const float* __restrict__ Zq, const float* __restrict__ Zk,
    const float* __restrict__ Wq_w, const float* __restrict__ Wq_b,
    const float* __restrict__ Wk_w, const float* __restrict__ Wk_b,
    float* __restrict__ Qbuf, float* __restrict__ Kbuf)
{
    int b = blockIdx.x;          // 0 .. 2*TT-1
    int c = b / TT, t = b % TT;
    __shared__ float zq[DD], zk[DD];
    int tid = threadIdx.x;
    if (tid < DD) zq[tid] = Zq[(c*TT + t)*DD + tid];
    else          zk[tid-DD] = Zk[(c*TT + t)*DD + (tid-DD)];
    __syncthreads();
    int o = tid & 63;
    const float* __restrict__ W  = (tid < 64) ? Wq_w : Wk_w;
    const float* __restrict__ bs = (tid < 64) ? Wq_b : Wk_b;
    const float* __restrict__ z  = (tid < 64) ? zq : zk;
    float* __restrict__ dst      = (tid < 64) ? Qbuf : Kbuf;
    float acc = bs[o];
    #pragma unroll
    for (int i4 = 0; i4 < 16; ++i4) {
        f4 w4 = *(const f4*)&W[o*DD + i4*4];
        acc = fmaf(z[i4*4+0], w4.x, acc);
        acc = fmaf(z[i4*4+1], w4.y, acc);
        acc = fmaf(z[i4*4+2], w4.z, acc);
        acc = fmaf(z[i4*4+3], w4.w, acc);
    }
    dst[(c*TT + t)*DD + o] = acc;
}

// ---------------- tiny outputs + per-d constant tables --------------------
__global__ __launch_bounds__(64) void afa_tail_kernel(
    const float* __restrict__ l1, const float* __restrict__ t_all,
    const float* __restrict__ lOm_, const float* __restrict__ lGa_,
    const float* __restrict__ lC,
    float* __restrict__ ws, float* __restrict__ out)
{
    int d = threadIdx.x;
    int h = d & 31;
    float a  = -fabsf(l1[h]);
    float bb = (d < 32) ? l1[32 + h] : -l1[32 + h];
    out[O_LH + d]      = a;
    out[O_LH + DD + d] = bb;
    float dT = t_all[TT] - t_all[TT-1];
    float me = __expf(a * dT);
    out[O_ME + d]      = me * __cosf(bb * dT);
    out[O_ME + DD + d] = me * __sinf(bb * dT);
    ws[W_CA + d] = a;
    ws[W_CB + d] = bb;
    ws[W_CC + d] = lC[d] * fabsf(lOm_[d]) / (-2.0f * a + EPSF);
    ws[W_CG + d] = fabsf(lGa_[d]) + EPSF;
}

// ---------------- fused row kernel: Zhat + softmax + Q_ij + est_latent ----
// one block per row i, 512 threads = 8 waves; 2 blocks/CU.
// lane layout: jg = (lane>>4) picks j within wave-iter, d0 = (lane&15)*4.
__global__ __launch_bounds__(512, 4) void afa_row_kernel(
    const float* __restrict__ Zv, const float* __restrict__ t_all,
    const float* __restrict__ nf,  const float* __restrict__ tau_,
    const float* __restrict__ nu_, const float* __restrict__ etap,
    const float* __restrict__ ws, float* __restrict__ out)
{
    const float* Qbuf = ws + W_QBUF;
    const float* Kbuf = ws + W_KBUF;

    int bid = blockIdx.x;
    int i = (bid & 1) ? (TT - 1 - (bid >> 1)) : (bid >> 1);
    int tid = threadIdx.x;
    int w  = tid >> 6;               // wave 0..7
    int l  = tid & 63;
    int jg = l >> 4;                 // 0..3
    int d0 = (l & 15) * 4;           // 0,4,...,60

    __shared__ float t_lds[TT];
    __shared__ float sij[TT];
    __shared__ float lsS[8][DD], lsR[8][DD], lsI[8][DD];
    __shared__ float invS[DD];

    t_lds[tid] = t_all[tid];         // 512 threads, 512 entries

    f4 A4 = *(const f4*)&ws[W_CA + d0];
    f4 B4 = *(const f4*)&ws[W_CB + d0];
    f4 C4 = *(const f4*)&ws[W_CC + d0];
    f4 G4 = *(const f4*)&ws[W_CG + d0];
    const float* A = (const float*)&A4;
    const float* B = (const float*)&B4;
    const float* C = (const float*)&C4;
    const float* G = (const float*)&G4;
    float noise = fabsf(nf[0]);
    float tau_a = fabsf(tau_[0]);
    float nu_a  = fabsf(nu_[0]);
    float ti = t_all[i];
    f4 QR4 = *(const f4*)&Qbuf[i*DD + d0];
    f4 QI4 = *(const f4*)&Qbuf[TT*DD + i*DD + d0];
    const float* QR = (const float*)&QR4;
    const float* QI = (const float*)&QI4;

    float* __restrict__ Qout  = out + O_QIJ  + (size_t)i*TT*DD;
    float* __restrict__ Z0out = out + O_ZHAT + (size_t)i*TT*DD;
    float* __restrict__ Z1out = out + O_ZHAT + (size_t)TT*TT*DD + (size_t)i*TT*DD;

    __syncthreads();

    // ---- Phase 1: Zhat stream + mah -> sij (LDS) + softmax partials ------
    // software-pipelined: K/V loads for j+32 issued before computing j.
    float s[4]  = {0.f,0.f,0.f,0.f};
    float ar[4] = {0.f,0.f,0.f,0.f};
    float ai[4] = {0.f,0.f,0.f,0.f};
    f4 zz4 = (f4)(0.0f);

    f4 KR4 = zz4, KI4 = zz4, VR4 = zz4, VI4 = zz4;
    {
        int jf = w*4 + jg;
        if (jf <= i) {
            KR4 = *(const f4*)&Kbuf[jf*DD + d0];
            KI4 = *(const f4*)&Kbuf[TT*DD + jf*DD + d0];
            VR4 = *(const f4*)&Zv[jf*DD + d0];
            VI4 = *(const f4*)&Zv[TT*DD + jf*DD + d0];
        }
    }
    for (int j0 = w*4; j0 < TT; j0 += 32) {
        int j = j0 + jg;
        f4 kr4 = KR4, ki4 = KI4, vr4 = VR4, vi4 = VI4;
        int jn = j + 32;
        if (jn <= i) {                       // prefetch next causal iter
            KR4 = *(const f4*)&Kbuf[jn*DD + d0];
            KI4 = *(const f4*)&Kbuf[TT*DD + jn*DD + d0];
            VR4 = *(const f4*)&Zv[jn*DD + d0];
            VI4 = *(const f4*)&Zv[TT*DD + jn*DD + d0];
        }
        if (j <= i) {
            float dt = ti - t_lds[j];
            const float* KR = (const float*)&kr4;
            const float* KI = (const float*)&ki4;
            const float* VR = (const float*)&vr4;
            const float* VI = (const float*)&vi4;
            float e[4], cs[4], sn[4], ZR[4], ZI[4];
            #pragma unroll
            for (int k = 0; k < 4; ++k) {
                e[k]  = __expf(A[k] * dt);
                float ang = B[k] * dt;
                cs[k] = __cosf(ang); sn[k] = __sinf(ang);
                ZR[k] = e[k] * (cs[k]*VR[k] - sn[k]*VI[k]);
                ZI[k] = e[k] * (sn[k]*VR[k] + cs[k]*VI[k]);
            }
            // Zhat does not depend on the reduction: store immediately
            f4 z0, z1;
            float* Z0 = (float*)&z0;
            float* Z1 = (float*)&z1;
            #pragma unroll
            for (int k = 0; k < 4; ++k) { Z0[k] = ZR[k]; Z1[k] = ZI[k]; }
            __builtin_nontemporal_store(z0, (f4*)&Z0out[(size_t)j*DD + d0]);
            __builtin_nontemporal_store(z1, (f4*)&Z1out[(size_t)j*DD + d0]);

            float Vij[4];
            float mah = 0.f;
            #pragma unroll
            for (int k = 0; k < 4; ++k) {
                float Rr = QR[k] - e[k] * (cs[k]*KR[k] - sn[k]*KI[k]);
                float Ri = QI[k] - e[k] * (sn[k]*KR[k] + cs[k]*KI[k]);
                Vij[k] = C[k] * (1.0f - e[k]*e[k]);
                mah += (Rr*Rr + Ri*Ri) / (Vij[k] + G[k]);
            }
            // reduce over 16-lane d-group (uniform branch per group)
            mah += __shfl_xor(mah, 1);
            mah += __shfl_xor(mah, 2);
            mah += __shfl_xor(mah, 4);
            mah += __shfl_xor(mah, 8);
            if ((l & 15) == 0) sij[j] = mah;
            float w1 = noise + nu_a * mah;
            #pragma unroll
            for (int k = 0; k < 4; ++k) {
                float base = Vij[k] * w1;
                float sc = -tau_a * __logf(base + EPSF);
                float p  = __expf(sc);            // fixed-ref M=0 (scores bounded)
                s[k]  += p;
                ar[k] = fmaf(p, ZR[k], ar[k]);
                ai[k] = fmaf(p, ZI[k], ai[k]);
            }
        } else {
            __builtin_nontemporal_store(zz4, (f4*)&Z0out[(size_t)j*DD + d0]);
            __builtin_nontemporal_store(zz4, (f4*)&Z1out[(size_t)j*DD + d0]);
        }
    }
    // combine jg groups within the wave (lanes l, l^16, l^32 share d0)
    #pragma unroll
    for (int k = 0; k < 4; ++k) {
        s[k]  += __shfl_xor(s[k], 16);  s[k]  += __shfl_xor(s[k], 32);
        ar[k] += __shfl_xor(ar[k], 16); ar[k] += __shfl_xor(ar[k], 32);
        ai[k] += __shfl_xor(ai[k], 16); ai[k] += __shfl_xor(ai[k], 32);
    }
    if (jg == 0) {
        #pragma unroll
        for (int k = 0; k < 4; ++k) {
            lsS[w][d0+k] = s[k];
            lsR[w][d0+k] = ar[k];
            lsI[w][d0+k] = ai[k];
        }
    }
    __syncthreads();
    if (tid < 64) {
        float S = 0.f, AR = 0.f, AI = 0.f;
        #pragma unroll
        for (int ww = 0; ww < 8; ++ww) {
            S += lsS[ww][tid]; AR += lsR[ww][tid]; AI += lsI[ww][tid];
        }
        float inv = 1.0f / S;
        invS[tid] = inv;
        float eta = 1.0f / (1.0f + __expf(-etap[tid]));
        float vr = Zv[i*DD + tid], vi = Zv[TT*DD + i*DD + tid];
        out[O_EST + i*DD + tid]         = (1.0f - eta)*vr + eta*AR*inv;
        out[O_EST + TT*DD + i*DD + tid] = (1.0f - eta)*vi + eta*AI*inv;
    }
    __syncthreads();

    // ---- Phase 2: Q_ij stream from LDS sij ------------------------------
    int jl = tid >> 4;               // 0..31
    f4 inv4;
    inv4.x = invS[d0]; inv4.y = invS[d0+1]; inv4.z = invS[d0+2]; inv4.w = invS[d0+3];
    const float* IV = (const float*)&inv4;
    #pragma unroll 2
    for (int it = 0; it < 16; ++it) {
        int j = it*32 + jl;
        if (j <= i) {
            float dt = ti - t_lds[j];
            float w1 = noise + nu_a * sij[j];
            f4 q4;
            float* Q = (float*)&q4;
            #pragma unroll
            for (int k = 0; k < 4; ++k) {
                float e2  = __expf(2.0f * A[k] * dt);
                float base = C[k] * (1.0f - e2) * w1;
                float sc = -tau_a * __logf(base + EPSF);
                Q[k] = __expf(sc) * IV[k];
            }
            __builtin_nontemporal_store(q4, (f4*)&Qout[(size_t)j*DD + d0]);
        } else {
            __builtin_nontemporal_store(zz4, (f4*)&Qout[(size_t)j*DD + d0]);
        }
    }
}

extern "C" void kernel_launch(void* const* d_in, const int* in_sizes, int n_in,
                              void* d_out, int out_size, void* d_ws, size_t ws_size,
                              hipStream_t stream) {
    const float* Zq    = (const float*)d_in[0];
    const float* Zk    = (const float*)d_in[1];
    const float* Zv    = (const float*)d_in[2];
    const float* t_all = (const float*)d_in[3];
    const float* Wq_w  = (const float*)d_in[4];
    const float* Wq_b  = (const float*)d_in[5];
    const float* Wk_w  = (const float*)d_in[6];
    const float* Wk_b  = (const float*)d_in[7];
    const float* l1    = (const float*)d_in[8];
    const float* lOm   = (const float*)d_in[9];
    const float* lGa   = (const float*)d_in[10];
    const float* nf    = (const float*)d_in[11];
    const float* tau   = (const float*)d_in[12];
    const float* nu    = (const float*)d_in[13];
    const float* etap  = (const float*)d_in[14];
    const float* lC    = (const float*)d_in[15];
    float* out = (float*)d_out;
    float* ws  = (float*)d_ws;

    afa_proj_kernel<<<2*TT, 128, 0, stream>>>(Zq, Zk, Wq_w, Wq_b, Wk_w, Wk_b,
                                              ws + W_QBUF, ws + W_KBUF);
    afa_tail_kernel<<<1, 64, 0, stream>>>(l1, t_all, lOm, lGa, lC, ws, out);
    afa_row_kernel<<<TT, 512, 0, stream>>>(Zv, t_all, nf, tau, nu, etap, ws, out);
}

// Round 9
// 51.751 us; speedup vs baseline: 1.0894x; 1.0894x over previous
//
#include <hip/hip_runtime.h>
#include <math.h>

#define TT 512
#define DD 64
#define EPSF 1e-5f

typedef float f4 __attribute__((ext_vector_type(4)));

// output offsets (floats), concatenated in return order
#define O_EST  0                       // est_latent (1,2,512,64)
#define O_QIJ  (2*TT*DD)               // Q_ij (1,512,512,64)
#define O_ZHAT (O_QIJ + TT*TT*DD)      // Zhat (1,2,512,512,64)
#define O_LH   (O_ZHAT + 2*TT*TT*DD)   // lambda_h (2,64)
#define O_ME   (O_LH + 2*DD)           // mat_exp (1,2,64)

// ws layout (floats)
#define W_QBUF 0
#define W_KBUF (W_QBUF + 2*TT*DD)
#define W_CA   (W_KBUF + 2*TT*DD)          // a[d]
#define W_CB   (W_CA + DD)                 // bc[d]
#define W_CC   (W_CB + DD)                 // c1[d]
#define W_CG   (W_CC + DD)                 // lGa[d]

// ---------------- Q/K projection ----------------------------------------
__global__ __launch_bounds__(128) void afa_proj_kernel(
    const float* __restrict__ Zq, const float* __restrict__ Zk,
    const float* __restrict__ Wq_w, const float* __restrict__ Wq_b,
    const float* __restrict__ Wk_w, const float* __restrict__ Wk_b,
    float* __restrict__ Qbuf, float* __restrict__ Kbuf)
{
    int b = blockIdx.x;          // 0 .. 2*TT-1
    int c = b / TT, t = b % TT;
    __shared__ float zq[DD], zk[DD];
    int tid = threadIdx.x;
    if (tid < DD) zq[tid] = Zq[(c*TT + t)*DD + tid];
    else          zk[tid-DD] = Zk[(c*TT + t)*DD + (tid-DD)];
    __syncthreads();
    int o = tid & 63;
    const float* __restrict__ W  = (tid < 64) ? Wq_w : Wk_w;
    const float* __restrict__ bs = (tid < 64) ? Wq_b : Wk_b;
    const float* __restrict__ z  = (tid < 64) ? zq : zk;
    float* __restrict__ dst      = (tid < 64) ? Qbuf : Kbuf;
    float acc = bs[o];
    #pragma unroll
    for (int i4 = 0; i4 < 16; ++i4) {
        f4 w4 = *(const f4*)&W[o*DD + i4*4];
        acc = fmaf(z[i4*4+0], w4.x, acc);
        acc = fmaf(z[i4*4+1], w4.y, acc);
        acc = fmaf(z[i4*4+2], w4.z, acc);
        acc = fmaf(z[i4*4+3], w4.w, acc);
    }
    dst[(c*TT + t)*DD + o] = acc;
}

// ---------------- tiny outputs + per-d constant tables --------------------
__global__ __launch_bounds__(64) void afa_tail_kernel(
    const float* __restrict__ l1, const float* __restrict__ t_all,
    const float* __restrict__ lOm_, const float* __restrict__ lGa_,
    const float* __restrict__ lC,
    float* __restrict__ ws, float* __restrict__ out)
{
    int d = threadIdx.x;
    int h = d & 31;
    float a  = -fabsf(l1[h]);
    float bb = (d < 32) ? l1[32 + h] : -l1[32 + h];
    out[O_LH + d]      = a;
    out[O_LH + DD + d] = bb;
    float dT = t_all[TT] - t_all[TT-1];
    float me = __expf(a * dT);
    out[O_ME + d]      = me * __cosf(bb * dT);
    out[O_ME + DD + d] = me * __sinf(bb * dT);
    ws[W_CA + d] = a;
    ws[W_CB + d] = bb;
    ws[W_CC + d] = lC[d] * fabsf(lOm_[d]) / (-2.0f * a + EPSF);
    ws[W_CG + d] = fabsf(lGa_[d]) + EPSF;
}

// ---------------- fused pair kernel: rows (m, 511-m) per block ------------
// 256 blocks x 1024 threads (16 waves) = 1 block/CU, identical work/block.
// lane layout: w = tid>>6 (wave), jg = (lane>>4), d0 = (lane&15)*4.
__global__ __launch_bounds__(1024, 4) void afa_pair_kernel(
    const float* __restrict__ Zv, const float* __restrict__ t_all,
    const float* __restrict__ nf,  const float* __restrict__ tau_,
    const float* __restrict__ nu_, const float* __restrict__ etap,
    const float* __restrict__ ws, float* __restrict__ out)
{
    const float* Qbuf = ws + W_QBUF;
    const float* Kbuf = ws + W_KBUF;

    int m  = blockIdx.x;             // 0..255
    int iA = m;                      // light row
    int iB = TT - 1 - m;             // heavy row
    int tid = threadIdx.x;
    int w  = tid >> 6;               // wave 0..15
    int l  = tid & 63;
    int jg = l >> 4;                 // 0..3
    int d0 = (l & 15) * 4;           // 0,4,...,60

    __shared__ float t_lds[TT];
    __shared__ float sijA[TT], sijB[TT];
    __shared__ float lsS[16][DD], lsR[16][DD], lsI[16][DD];
    __shared__ float invSA[DD], invSB[DD];

    if (tid < TT) t_lds[tid] = t_all[tid];

    f4 A4 = *(const f4*)&ws[W_CA + d0];
    f4 B4 = *(const f4*)&ws[W_CB + d0];
    f4 C4 = *(const f4*)&ws[W_CC + d0];
    f4 G4 = *(const f4*)&ws[W_CG + d0];
    const float* A = (const float*)&A4;
    const float* B = (const float*)&B4;
    const float* C = (const float*)&C4;
    const float* G = (const float*)&G4;
    float noise = fabsf(nf[0]);
    float tau_a = fabsf(tau_[0]);
    float nu_a  = fabsf(nu_[0]);
    float tiA = t_all[iA];
    float tiB = t_all[iB];
    f4 QRA4 = *(const f4*)&Qbuf[iA*DD + d0];
    f4 QIA4 = *(const f4*)&Qbuf[TT*DD + iA*DD + d0];
    f4 QRB4 = *(const f4*)&Qbuf[iB*DD + d0];
    f4 QIB4 = *(const f4*)&Qbuf[TT*DD + iB*DD + d0];

    float* __restrict__ QoutA = out + O_QIJ  + (size_t)iA*TT*DD;
    float* __restrict__ Z0A   = out + O_ZHAT + (size_t)iA*TT*DD;
    float* __restrict__ Z1A   = out + O_ZHAT + (size_t)TT*TT*DD + (size_t)iA*TT*DD;
    float* __restrict__ QoutB = out + O_QIJ  + (size_t)iB*TT*DD;
    float* __restrict__ Z0B   = out + O_ZHAT + (size_t)iB*TT*DD;
    float* __restrict__ Z1B   = out + O_ZHAT + (size_t)TT*TT*DD + (size_t)iB*TT*DD;

    f4 zz4 = (f4)(0.0f);

    // phase-1 body: Zhat stores + mah -> sij + softmax partials
    auto P1 = [&](int j, int i, float ti, const f4& QRv, const f4& QIv,
                  float* __restrict__ sij_, float* __restrict__ Z0out,
                  float* __restrict__ Z1out,
                  float* s, float* ar, float* ai) {
        if (j <= i) {
            float dt = ti - t_lds[j];
            f4 KR4 = *(const f4*)&Kbuf[j*DD + d0];
            f4 KI4 = *(const f4*)&Kbuf[TT*DD + j*DD + d0];
            f4 VR4 = *(const f4*)&Zv[j*DD + d0];
            f4 VI4 = *(const f4*)&Zv[TT*DD + j*DD + d0];
            const float* KR = (const float*)&KR4;
            const float* KI = (const float*)&KI4;
            const float* VR = (const float*)&VR4;
            const float* VI = (const float*)&VI4;
            const float* QR = (const float*)&QRv;
            const float* QI = (const float*)&QIv;
            float e[4], cs[4], sn[4], ZR[4], ZI[4], Vij[4];
            float mah = 0.f;
            #pragma unroll
            for (int k = 0; k < 4; ++k) {
                e[k]  = __expf(A[k] * dt);
                float ang = B[k] * dt;
                cs[k] = __cosf(ang); sn[k] = __sinf(ang);
                ZR[k] = e[k] * (cs[k]*VR[k] - sn[k]*VI[k]);
                ZI[k] = e[k] * (sn[k]*VR[k] + cs[k]*VI[k]);
            }
            f4 z0, z1;
            float* Z0 = (float*)&z0;
            float* Z1 = (float*)&z1;
            #pragma unroll
            for (int k = 0; k < 4; ++k) { Z0[k] = ZR[k]; Z1[k] = ZI[k]; }
            __builtin_nontemporal_store(z0, (f4*)&Z0out[(size_t)j*DD + d0]);
            __builtin_nontemporal_store(z1, (f4*)&Z1out[(size_t)j*DD + d0]);
            #pragma unroll
            for (int k = 0; k < 4; ++k) {
                float Rr = QR[k] - e[k] * (cs[k]*KR[k] - sn[k]*KI[k]);
                float Ri = QI[k] - e[k] * (sn[k]*KR[k] + cs[k]*KI[k]);
                Vij[k] = C[k] * (1.0f - e[k]*e[k]);
                mah += (Rr*Rr + Ri*Ri) / (Vij[k] + G[k]);
            }
            mah += __shfl_xor(mah, 1);
            mah += __shfl_xor(mah, 2);
            mah += __shfl_xor(mah, 4);
            mah += __shfl_xor(mah, 8);
            if ((l & 15) == 0) sij_[j] = mah;
            float w1 = noise + nu_a * mah;
            #pragma unroll
            for (int k = 0; k < 4; ++k) {
                float base = Vij[k] * w1;
                float sc = -tau_a * __logf(base + EPSF);
                float p  = __expf(sc);            // fixed-ref M=0 (scores bounded)
                s[k]  += p;
                ar[k] = fmaf(p, ZR[k], ar[k]);
                ai[k] = fmaf(p, ZI[k], ai[k]);
            }
        } else {
            __builtin_nontemporal_store(zz4, (f4*)&Z0out[(size_t)j*DD + d0]);
            __builtin_nontemporal_store(zz4, (f4*)&Z1out[(size_t)j*DD + d0]);
        }
    };

    // phase-2 body: Q_ij stores from LDS sij
    auto P2 = [&](int j, int i, float ti, const float* IV,
                  const float* __restrict__ sij_, float* __restrict__ Qout) {
        if (j <= i) {
            float dt = ti - t_lds[j];
            float w1 = noise + nu_a * sij_[j];
            f4 q4;
            float* Q = (float*)&q4;
            #pragma unroll
            for (int k = 0; k < 4; ++k) {
                float e2  = __expf(2.0f * A[k] * dt);
                float base = C[k] * (1.0f - e2) * w1;
                float sc = -tau_a * __logf(base + EPSF);
                Q[k] = __expf(sc) * IV[k];
            }
            __builtin_nontemporal_store(q4, (f4*)&Qout[(size_t)j*DD + d0]);
        } else {
            __builtin_nontemporal_store(zz4, (f4*)&Qout[(size_t)j*DD + d0]);
        }
    };

    // wave-level jg-combine + LDS partial write
    auto COMBINE = [&](float* s, float* ar, float* ai) {
        #pragma unroll
        for (int k = 0; k < 4; ++k) {
            s[k]  += __shfl_xor(s[k], 16);  s[k]  += __shfl_xor(s[k], 32);
            ar[k] += __shfl_xor(ar[k], 16); ar[k] += __shfl_xor(ar[k], 32);
            ai[k] += __shfl_xor(ai[k], 16); ai[k] += __shfl_xor(ai[k], 32);
        }
        if (jg == 0) {
            #pragma unroll
            for (int k = 0; k < 4; ++k) {
                lsS[w][d0+k] = s[k];
                lsR[w][d0+k] = ar[k];
                lsI[w][d0+k] = ai[k];
            }
        }
    };

    __syncthreads();

    // ---- P1(A): light row ------------------------------------------------
    float sA[4]  = {0.f,0.f,0.f,0.f};
    float arA[4] = {0.f,0.f,0.f,0.f};
    float aiA[4] = {0.f,0.f,0.f,0.f};
    for (int it = 0; it < 8; ++it)
        P1(it*64 + w*4 + jg, iA, tiA, QRA4, QIA4, sijA, Z0A, Z1A, sA, arA, aiA);
    COMBINE(sA, arA, aiA);
    __syncthreads();
    if (tid < 64) {
        float S = 0.f, AR = 0.f, AI = 0.f;
        #pragma unroll
        for (int ww = 0; ww < 16; ++ww) {
            S += lsS[ww][tid]; AR += lsR[ww][tid]; AI += lsI[ww][tid];
        }
        float inv = 1.0f / S;
        invSA[tid] = inv;
        float eta = 1.0f / (1.0f + __expf(-etap[tid]));
        float vr = Zv[iA*DD + tid], vi = Zv[TT*DD + iA*DD + tid];
        out[O_EST + iA*DD + tid]         = (1.0f - eta)*vr + eta*AR*inv;
        out[O_EST + TT*DD + iA*DD + tid] = (1.0f - eta)*vi + eta*AI*inv;
    }
    __syncthreads();

    // ---- P2(A) interleaved with P1(B): zero-heavy stores hide B's chains -
    f4 invA4;
    invA4.x = invSA[d0]; invA4.y = invSA[d0+1];
    invA4.z = invSA[d0+2]; invA4.w = invSA[d0+3];
    const float* IVA = (const float*)&invA4;
    float sB[4]  = {0.f,0.f,0.f,0.f};
    float arB[4] = {0.f,0.f,0.f,0.f};
    float aiB[4] = {0.f,0.f,0.f,0.f};
    int jl = tid >> 4;               // 0..63
    for (int it = 0; it < 8; ++it) {
        P2(it*64 + jl, iA, tiA, IVA, sijA, QoutA);
        P1(it*64 + w*4 + jg, iB, tiB, QRB4, QIB4, sijB, Z0B, Z1B, sB, arB, aiB);
    }
    COMBINE(sB, arB, aiB);
    __syncthreads();
    if (tid < 64) {
        float S = 0.f, AR = 0.f, AI = 0.f;
        #pragma unroll
        for (int ww = 0; ww < 16; ++ww) {
            S += lsS[ww][tid]; AR += lsR[ww][tid]; AI += lsI[ww][tid];
        }
        float inv = 1.0f / S;
        invSB[tid] = inv;
        float eta = 1.0f / (1.0f + __expf(-etap[tid]));
        float vr = Zv[iB*DD + tid], vi = Zv[TT*DD + iB*DD + tid];
        out[O_EST + iB*DD + tid]         = (1.0f - eta)*vr + eta*AR*inv;
        out[O_EST + TT*DD + iB*DD + tid] = (1.0f - eta)*vi + eta*AI*inv;
    }
    __syncthreads();

    // ---- P2(B) -----------------------------------------------------------
    f4 invB4;
    invB4.x = invSB[d0]; invB4.y = invSB[d0+1];
    invB4.z = invSB[d0+2]; invB4.w = invSB[d0+3];
    const float* IVB = (const float*)&invB4;
    for (int it = 0; it < 8; ++it)
        P2(it*64 + jl, iB, tiB, IVB, sijB, QoutB);
}

extern "C" void kernel_launch(void* const* d_in, const int* in_sizes, int n_in,
                              void* d_out, int out_size, void* d_ws, size_t ws_size,
                              hipStream_t stream) {
    const float* Zq    = (const float*)d_in[0];
    const float* Zk    = (const float*)d_in[1];
    const float* Zv    = (const float*)d_in[2];
    const float* t_all = (const float*)d_in[3];
    const float* Wq_w  = (const float*)d_in[4];
    const float* Wq_b  = (const float*)d_in[5];
    const float* Wk_w  = (const float*)d_in[6];
    const float* Wk_b  = (const float*)d_in[7];
    const float* l1    = (const float*)d_in[8];
    const float* lOm   = (const float*)d_in[9];
    const float* lGa   = (const float*)d_in[10];
    const float* nf    = (const float*)d_in[11];
    const float* tau   = (const float*)d_in[12];
    const float* nu    = (const float*)d_in[13];
    const float* etap  = (const float*)d_in[14];
    const float* lC    = (const float*)d_in[15];
    float* out = (float*)d_out;
    float* ws  = (float*)d_ws;

    afa_proj_kernel<<<2*TT, 128, 0, stream>>>(Zq, Zk, Wq_w, Wq_b, Wk_w, Wk_b,
                                              ws + W_QBUF, ws + W_KBUF);
    afa_tail_kernel<<<1, 64, 0, stream>>>(l1, t_all, lOm, lGa, lC, ws, out);
    afa_pair_kernel<<<TT/2, 1024, 0, stream>>>(Zv, t_all, nf, tau, nu, etap,
                                               ws, out);
}